// Round 22
// baseline (82.889 us; speedup 1.0000x reference)
//
#include <hip/hip_runtime.h>

// NCC loss (B=2, C=1, 160^3 f32, 9^3 box window). Three axis passes + reduce.
// Principle (from 21 rounds): one axis per kernel; sliding passes read
// coalesced-staged contiguous LDS strips; transpose on the WRITE side.
// pass_x : one-shot 9-wide x-window on f32 I/J (inline products, 16-value
//          register neighborhood) -> fp8 bufA [b][y][z][f][x] (z-contig rows).
// pass_z2: stage 48 CONTIGUOUS row-groups (38.4 KB) from bufA, slide 9-tap
//          z-window in LDS, write transposed -> fp8 bufB [b][z][y][f][x].
// pass_y2: (R18 verbatim) stage 48 contiguous rows from bufB, slide 9-tap
//          y-window + cc + deterministic reduction.
// finalize: deterministic reduce.

typedef float floatx2 __attribute__((ext_vector_type(2)));

constexpr int W = 160, H = 160, D = 160;
constexpr int SLICE = W * H;
constexpr int NVOX  = W * H * D;
constexpr int BATCH = 2;
constexpr int FROW  = 5 * W;             // 800 B per row-group
constexpr float RW  = 1.0f / 729.0f;

// pass_x geometry
constexpr int TPB_X = 256;
constexpr int XU    = W / 8;             // 20 8-x units per row
constexpr int NTH_X = BATCH * D * H * XU;        // 1,024,000
constexpr int NBLK_X = NTH_X / TPB_X;            // 4000

// pass_z2 geometry (staged slide, z axis; contiguous reads from [b][y][z])
constexpr int TPB_Z = 448;               // 7 waves
constexpr int ZQ    = 40;                // z outputs per block
constexpr int NZQ   = D / ZQ;            // 4
constexpr int ZR    = ZQ + 8;            // 48 staged rows
constexpr int NBLK_Z = BATCH * H * NZQ;  // 1280
constexpr int LDWZ  = ZR * FROW / 16;    // 2400 uint4 stage loads

// pass_y2 geometry (R18 verbatim)
constexpr int TPB_Y = 448;
constexpr int YQ    = 40;
constexpr int NYQ   = H / YQ;            // 4
constexpr int YR    = YQ + 8;            // 48
constexpr int NBLK_Y = BATCH * D * NYQ;  // 1280
constexpr int LDWY  = YR * FROW / 16;    // 2400

// ---- fp8 helpers (HW cvt, OCP e4m3) --------------------------------------
__device__ inline unsigned int pk4(float a, float b, float c, float d) {
    unsigned int u = 0;
    u = __builtin_amdgcn_cvt_pk_fp8_f32(a, b, u, false);
    u = __builtin_amdgcn_cvt_pk_fp8_f32(c, d, u, true);
    return u;
}
__device__ inline void up4(unsigned int v, float* o) {
    floatx2 t;
    t = __builtin_amdgcn_cvt_pk_f32_fp8(v, false); o[0] = t[0]; o[1] = t[1];
    t = __builtin_amdgcn_cvt_pk_f32_fp8(v, true);  o[2] = t[0]; o[3] = t[1];
}
__device__ inline void up8(uint2 v, float* o) {
    up4(v.x, o); up4(v.y, o + 4);
}

// ---- pass 1: one-shot x-window on f32 inputs -> bufA [b][y][z] -----------
__global__ __launch_bounds__(TPB_X) void pass_x(const float* __restrict__ I,
                                                const float* __restrict__ J,
                                                unsigned char* __restrict__ outA) {
    int t = blockIdx.x * TPB_X + threadIdx.x;
    int xu  = t % XU;
    int row = t / XU;                    // (b*D+z)*H + y
    int y = row % H;
    int zb = row / H;
    int z = zb % D;
    int b = zb / D;
    int x0 = xu * 8;

    const float* ip = I + (size_t)row * W + x0;
    const float* jp = J + (size_t)row * W + x0;
    const float4 Z4 = make_float4(0.f, 0.f, 0.f, 0.f);
    bool hasL = xu > 0, hasR = xu < XU - 1;

    // neighborhood x0-4 .. x0+11 (all 16B-aligned quads)
    float4 a0 = hasL ? *(const float4*)(ip - 4) : Z4;
    float4 a1 = *(const float4*)(ip);
    float4 a2 = *(const float4*)(ip + 4);
    float4 a3 = hasR ? *(const float4*)(ip + 8) : Z4;
    float4 c0 = hasL ? *(const float4*)(jp - 4) : Z4;
    float4 c1 = *(const float4*)(jp);
    float4 c2 = *(const float4*)(jp + 4);
    float4 c3 = hasR ? *(const float4*)(jp + 8) : Z4;

    float a[16] = {a0.x,a0.y,a0.z,a0.w, a1.x,a1.y,a1.z,a1.w,
                   a2.x,a2.y,a2.z,a2.w, a3.x,a3.y,a3.z,a3.w};
    float c[16] = {c0.x,c0.y,c0.z,c0.w, c1.x,c1.y,c1.z,c1.w,
                   c2.x,c2.y,c2.z,c2.w, c3.x,c3.y,c3.z,c3.w};

    unsigned char* op = outA + ((size_t)(b * H + y) * D + z) * FROW + x0;
#pragma unroll
    for (int f = 0; f < 5; ++f) {
        float v[16];
#pragma unroll
        for (int k = 0; k < 16; ++k) {
            float x = a[k], yv = c[k];
            v[k] = (f == 0) ? x : (f == 1) ? yv :
                   (f == 2) ? x * x : (f == 3) ? yv * yv : x * yv;
        }
        float P[16];
        P[0] = v[0];
#pragma unroll
        for (int k = 1; k < 16; ++k) P[k] = P[k - 1] + v[k];
        float w[8];
        w[0] = P[8];
#pragma unroll
        for (int j = 1; j < 8; ++j) w[j] = P[j + 8] - P[j - 1];
        uint2 pk;
        pk.x = pk4(w[0], w[1], w[2], w[3]);
        pk.y = pk4(w[4], w[5], w[6], w[7]);
        *(uint2*)(op + f * W) = pk;
    }
}

// ---- pass 2: staged z-slide (contiguous reads) -> bufB [b][z][y] ---------
__global__ __launch_bounds__(TPB_Z) void pass_z2(const unsigned char* __restrict__ A,
                                                 unsigned char* __restrict__ B) {
    __shared__ unsigned char rows[ZR * FROW];   // 38,400 B

    int blk = blockIdx.x;
    int zq = blk % NZQ;
    int y  = (blk / NZQ) % H;
    int b  = blk / (NZQ * H);
    int z0 = zq * ZQ;
    int tid = threadIdx.x;
    const unsigned char* __restrict__ src =
        A + ((size_t)(b * H + y) * D) * FROW;    // z-contiguous

    // stage 48 row-groups (contiguous span z0-4 .. z0+43); OOB -> zero
    for (int i = tid; i < LDWZ; i += TPB_Z) {
        int off = i * 16;
        int r = off / FROW;
        int gz = z0 - 4 + r;
        uint4 v = make_uint4(0u, 0u, 0u, 0u);
        if (gz >= 0 && gz < D)
            v = *(const uint4*)(src + (size_t)gz * FROW + (off % FROW));
        *(uint4*)&rows[off] = v;
    }
    __syncthreads();

    // compute: 20 xg x 20 z-strips (2 outputs each), slide over LDS
    if (tid < 400) {
        int xg = tid % 20;
        int zs = tid / 20;               // 0..19
        int rbase = zs * 2;
        int x8 = xg * 8;

        float s[5][8];
#pragma unroll
        for (int f = 0; f < 5; ++f)
#pragma unroll
            for (int i = 0; i < 8; ++i) s[f][i] = 0.f;

#pragma unroll
        for (int tt = 0; tt < 9; ++tt) {
            const unsigned char* rp = &rows[(rbase + tt) * FROW + x8];
#pragma unroll
            for (int f = 0; f < 5; ++f) {
                uint2 v = *(const uint2*)(rp + f * W);
                float u[8]; up8(v, u);
#pragma unroll
                for (int i = 0; i < 8; ++i) s[f][i] += u[i];
            }
        }

#pragma unroll
        for (int o = 0; o < 2; ++o) {
            int gzo = z0 + rbase + o;
            // transposed write: bufB [b][z][y]
            unsigned char* op = B + ((size_t)(b * D + gzo) * H + y) * FROW + x8;
#pragma unroll
            for (int f = 0; f < 5; ++f) {
                uint2 pk;
                pk.x = pk4(s[f][0], s[f][1], s[f][2], s[f][3]);
                pk.y = pk4(s[f][4], s[f][5], s[f][6], s[f][7]);
                *(uint2*)(op + f * W) = pk;
            }
            if (o == 0) {
                const unsigned char* re = &rows[(rbase + 9) * FROW + x8];
                const unsigned char* rl = &rows[rbase * FROW + x8];
#pragma unroll
                for (int f = 0; f < 5; ++f) {
                    uint2 ve = *(const uint2*)(re + f * W);
                    uint2 vl = *(const uint2*)(rl + f * W);
                    float ue[8], ul[8];
                    up8(ve, ue); up8(vl, ul);
#pragma unroll
                    for (int i = 0; i < 8; ++i) s[f][i] += ue[i] - ul[i];
                }
            }
        }
    }
}

// ---- pass 3: LDS-staged y-slide + cc + reduce (R18 verbatim) -------------
__global__ __launch_bounds__(TPB_Y) void pass_y2(const unsigned char* __restrict__ A,
                                                 double* __restrict__ partials) {
    __shared__ unsigned char rows[YR * FROW];   // 38,400 B fp8
    __shared__ double sm[TPB_Y / 64];

    int blk = blockIdx.x;
    int yq = blk % NYQ;
    int z  = (blk / NYQ) % D;
    int b  = blk / (NYQ * D);
    int y0 = yq * YQ;
    int tid = threadIdx.x;
    const unsigned char* __restrict__ src =
        A + ((size_t)(b * D + z) * H) * FROW;

    for (int i = tid; i < LDWY; i += TPB_Y) {
        int off = i * 16;
        int r = off / FROW;
        int gy = y0 - 4 + r;
        uint4 v = make_uint4(0u, 0u, 0u, 0u);
        if (gy >= 0 && gy < H)
            v = *(const uint4*)(src + (size_t)gy * FROW + (off % FROW));
        *(uint4*)&rows[off] = v;
    }
    __syncthreads();

    double acc = 0.0;
    if (tid < 400) {
        int xg = tid % 20;
        int ys = tid / 20;
        int rbase = ys * 2;
        int x8 = xg * 8;

        float s[5][8];
#pragma unroll
        for (int f = 0; f < 5; ++f)
#pragma unroll
            for (int i = 0; i < 8; ++i) s[f][i] = 0.f;

#pragma unroll
        for (int t = 0; t < 9; ++t) {
            const unsigned char* rp = &rows[(rbase + t) * FROW + x8];
#pragma unroll
            for (int f = 0; f < 5; ++f) {
                uint2 v = *(const uint2*)(rp + f * W);
                float u[8]; up8(v, u);
#pragma unroll
                for (int i = 0; i < 8; ++i) s[f][i] += u[i];
            }
        }

#pragma unroll
        for (int o = 0; o < 2; ++o) {
            float rowcc = 0.f;
#pragma unroll
            for (int i = 0; i < 8; ++i) {
                float Is = s[0][i], Js = s[1][i];
                float I2s = s[2][i], J2s = s[3][i], IJs = s[4][i];
                float tI = RW * Is;
                float cross = __builtin_fmaf(-tI, Js, IJs);
                float Iv    = __builtin_fmaf(-tI, Is, I2s);
                float Jv    = __builtin_fmaf(-(RW * Js), Js, J2s);
                float den   = __builtin_fmaf(Iv, Jv, 1e-5f);
                rowcc = __builtin_fmaf(cross * cross, __builtin_amdgcn_rcpf(den), rowcc);
            }
            acc += (double)rowcc;
            if (o == 0) {
                const unsigned char* re = &rows[(rbase + 9) * FROW + x8];
                const unsigned char* rl = &rows[rbase * FROW + x8];
#pragma unroll
                for (int f = 0; f < 5; ++f) {
                    uint2 ve = *(const uint2*)(re + f * W);
                    uint2 vl = *(const uint2*)(rl + f * W);
                    float ue[8], ul[8];
                    up8(ve, ue); up8(vl, ul);
#pragma unroll
                    for (int i = 0; i < 8; ++i) s[f][i] += ue[i] - ul[i];
                }
            }
        }
    }

#pragma unroll
    for (int off = 32; off > 0; off >>= 1) acc += __shfl_down(acc, off);
    if ((tid & 63) == 0) sm[tid >> 6] = acc;
    __syncthreads();
    if (tid == 0) {
        double tt = 0.0;
#pragma unroll
        for (int i = 0; i < TPB_Y / 64; ++i) tt += sm[i];
        partials[blockIdx.x] = tt;
    }
}

// ---- final deterministic reduce ------------------------------------------
__global__ __launch_bounds__(256) void finalize(const double* __restrict__ p,
                                                float* __restrict__ out) {
    double v = 0.0;
    for (int i = threadIdx.x; i < NBLK_Y; i += 256) v += p[i];
#pragma unroll
    for (int off = 32; off > 0; off >>= 1) v += __shfl_down(v, off);
    __shared__ double sm[4];
    int lane = threadIdx.x & 63, wid = threadIdx.x >> 6;
    if (lane == 0) sm[wid] = v;
    __syncthreads();
    if (threadIdx.x == 0) {
        double tt = 0.0;
#pragma unroll
        for (int i = 0; i < 4; ++i) tt += sm[i];
        out[0] = (float)(1.0 - tt / (double)((double)BATCH * (double)NVOX));
    }
}

extern "C" void kernel_launch(void* const* d_in, const int* in_sizes, int n_in,
                              void* d_out, int out_size, void* d_ws, size_t ws_size,
                              hipStream_t stream) {
    const float* I = (const float*)d_in[0];
    const float* J = (const float*)d_in[1];
    float* out = (float*)d_out;

    // ws: bufA (41 MB, [b][y][z]) | bufB (41 MB, [b][z][y]) | partials
    size_t bufsz = ((size_t)BATCH * 5 * NVOX + 255) / 256 * 256;
    unsigned char* bufA = (unsigned char*)d_ws;
    unsigned char* bufB = bufA + bufsz;
    double* partials = (double*)(bufB + bufsz);

    pass_x<<<NBLK_X, TPB_X, 0, stream>>>(I, J, bufA);
    pass_z2<<<NBLK_Z, TPB_Z, 0, stream>>>(bufA, bufB);
    pass_y2<<<NBLK_Y, TPB_Y, 0, stream>>>(bufB, partials);
    finalize<<<1, 256, 0, stream>>>(partials, out);
}

// Round 23
// 59.441 us; speedup vs baseline: 1.3945x; 1.3945x over previous
//
#include <hip/hip_runtime.h>

// NCC loss (B=2, C=1, 160^3 f32, 9^3 box window). Two passes + reduce.
// === R18 configuration (session best: 59.8 us) — reverted verbatim ===
// pass_pzx: block=(b,y,xt 80,zc 80). Staging: x-windowed products (prefix
//           over 16 per 8-x unit) -> fp8 LDS [5][88][80] (35.2 KB), one
//           barrier. Compute: 400 threads (20 xg x 20 zl), each slides a
//           9-tap z-window across 4 z outputs -> fp8 bufA [b][z][y][f][x].
// pass_y2 : block=(b,z,y-quarter 40). Stage 48 row-groups (38.4 KB)
//           coalesced into LDS, slide 9-tap y-window over LDS rows + cc +
//           deterministic reduction.
// finalize: deterministic reduce.

typedef float floatx2 __attribute__((ext_vector_type(2)));

constexpr int W = 160, H = 160, D = 160;
constexpr int SLICE = W * H;
constexpr int NVOX  = W * H * D;
constexpr int BATCH = 2;
constexpr int FROW  = 5 * W;             // 800 B per (b,z,y) row-group
constexpr float RW  = 1.0f / 729.0f;

// pass_pzx geometry
constexpr int TPB_P = 400;
constexpr int XT    = 80;                // x-tile width
constexpr int NXT   = W / XT;            // 2
constexpr int CZ    = 80;                // z outputs per block
constexpr int NCZ   = D / CZ;            // 2
constexpr int ZS    = CZ + 8;            // 88 staged slices
constexpr int NUNITS = ZS * 10;          // 880 staging units
constexpr int NBLK_P = BATCH * H * NXT * NCZ;    // 1280

// pass_y2 geometry
constexpr int TPB_Y = 448;               // 7 waves
constexpr int YQ    = 40;                // y outputs per block
constexpr int NYQ   = H / YQ;            // 4
constexpr int YR    = YQ + 8;            // 48 staged rows
constexpr int NBLK_Y = BATCH * D * NYQ;  // 1280
constexpr int LDW   = YR * FROW / 16;    // 2400 uint4 stage loads

// ---- fp8 helpers (HW cvt, OCP e4m3) --------------------------------------
__device__ inline unsigned int pk4(float a, float b, float c, float d) {
    unsigned int u = 0;
    u = __builtin_amdgcn_cvt_pk_fp8_f32(a, b, u, false);
    u = __builtin_amdgcn_cvt_pk_fp8_f32(c, d, u, true);
    return u;
}
__device__ inline void up4(unsigned int v, float* o) {
    floatx2 t;
    t = __builtin_amdgcn_cvt_pk_f32_fp8(v, false); o[0] = t[0]; o[1] = t[1];
    t = __builtin_amdgcn_cvt_pk_f32_fp8(v, true);  o[2] = t[0]; o[3] = t[1];
}
__device__ inline void up8(uint2 v, float* o) {
    up4(v.x, o); up4(v.y, o + 4);
}

// ---- pass 1: x-window at staging -> fp8 LDS; 4-z sliding z-window --------
__global__ __launch_bounds__(TPB_P) void pass_pzx(const float* __restrict__ I,
                                                  const float* __restrict__ J,
                                                  unsigned char* __restrict__ outA) {
    __shared__ unsigned char xw[5][ZS][XT];    // fp8, 35,200 B

    int blk = blockIdx.x;
    int zc = blk % NCZ;
    int xt = (blk / NCZ) % NXT;
    int y  = (blk / (NCZ * NXT)) % H;
    int b  = blk / (NCZ * NXT * H);
    int tx0 = xt * XT;
    int zbase = zc * CZ - 4;
    const float* Ib = I + (size_t)b * NVOX + y * W;
    const float* Jb = J + (size_t)b * NVOX + y * W;

    // ---- staging: 880 (slice, 8-x) units over 400 threads ----------------
    const float4 Z4 = make_float4(0.f, 0.f, 0.f, 0.f);
    for (int u = threadIdx.x; u < NUNITS; u += TPB_P) {
        int zs = u / 10;
        int xu = u % 10;
        int gxs = tx0 + xu * 8;
        int gz = zbase + zs;
        float a[16], c[16];
        if (gz >= 0 && gz < D) {
            const float* ip = Ib + (size_t)gz * SLICE + gxs;
            const float* jp = Jb + (size_t)gz * SLICE + gxs;
            float4 A0 = (gxs >= 4)     ? *(const float4*)(ip - 4) : Z4;
            float4 A1 = *(const float4*)(ip);
            float4 A2 = *(const float4*)(ip + 4);
            float4 A3 = (gxs + 11 < W) ? *(const float4*)(ip + 8) : Z4;
            float4 C0 = (gxs >= 4)     ? *(const float4*)(jp - 4) : Z4;
            float4 C1 = *(const float4*)(jp);
            float4 C2 = *(const float4*)(jp + 4);
            float4 C3 = (gxs + 11 < W) ? *(const float4*)(jp + 8) : Z4;
            float at[16] = {A0.x,A0.y,A0.z,A0.w, A1.x,A1.y,A1.z,A1.w,
                            A2.x,A2.y,A2.z,A2.w, A3.x,A3.y,A3.z,A3.w};
            float ct[16] = {C0.x,C0.y,C0.z,C0.w, C1.x,C1.y,C1.z,C1.w,
                            C2.x,C2.y,C2.z,C2.w, C3.x,C3.y,C3.z,C3.w};
#pragma unroll
            for (int k = 0; k < 16; ++k) { a[k] = at[k]; c[k] = ct[k]; }
        } else {
#pragma unroll
            for (int k = 0; k < 16; ++k) { a[k] = 0.f; c[k] = 0.f; }
        }
#pragma unroll
        for (int f = 0; f < 5; ++f) {
            float v[16];
#pragma unroll
            for (int k = 0; k < 16; ++k) {
                float x = a[k], yv = c[k];
                v[k] = (f == 0) ? x : (f == 1) ? yv :
                       (f == 2) ? x * x : (f == 3) ? yv * yv : x * yv;
            }
            float P[16];
            P[0] = v[0];
#pragma unroll
            for (int k = 1; k < 16; ++k) P[k] = P[k - 1] + v[k];
            float w[8];
            w[0] = P[8];
#pragma unroll
            for (int j = 1; j < 8; ++j) w[j] = P[j + 8] - P[j - 1];
            uint2 pk;
            pk.x = pk4(w[0], w[1], w[2], w[3]);
            pk.y = pk4(w[4], w[5], w[6], w[7]);
            *(uint2*)&xw[f][zs][xu * 8] = pk;
        }
    }

    __syncthreads();

    // ---- compute: 20 xg (4x) x 20 zl (4z each), sliding 9-tap z-window ---
    {
        int xg = threadIdx.x % 20;
        int zl = threadIdx.x / 20;       // 0..19
        int x0l = xg * 4;
        int zo0 = zl * 4;                // lds slice index of first output

        float acc[5][4];
#pragma unroll
        for (int f = 0; f < 5; ++f)
#pragma unroll
            for (int i = 0; i < 4; ++i) acc[f][i] = 0.f;

        // init window: lds slices zo0 .. zo0+8
#pragma unroll
        for (int k = 0; k < 9; ++k) {
#pragma unroll
            for (int f = 0; f < 5; ++f) {
                unsigned int v = *(const unsigned int*)&xw[f][zo0 + k][x0l];
                float u[4]; up4(v, u);
                acc[f][0] += u[0]; acc[f][1] += u[1];
                acc[f][2] += u[2]; acc[f][3] += u[3];
            }
        }

        int gz0 = zc * CZ + zo0;
        unsigned char* op = outA + ((size_t)(b * D + gz0) * H + y) * FROW + tx0 + x0l;
#pragma unroll
        for (int q = 0; q < 4; ++q) {
#pragma unroll
            for (int f = 0; f < 5; ++f)
                *(unsigned int*)(op + f * W) =
                    pk4(acc[f][0], acc[f][1], acc[f][2], acc[f][3]);
            if (q < 3) {
#pragma unroll
                for (int f = 0; f < 5; ++f) {
                    unsigned int ve = *(const unsigned int*)&xw[f][zo0 + 9 + q][x0l];
                    unsigned int vl = *(const unsigned int*)&xw[f][zo0 + q][x0l];
                    float ue[4], ul[4];
                    up4(ve, ue); up4(vl, ul);
                    acc[f][0] += ue[0] - ul[0]; acc[f][1] += ue[1] - ul[1];
                    acc[f][2] += ue[2] - ul[2]; acc[f][3] += ue[3] - ul[3];
                }
                op += (size_t)H * FROW;
            }
        }
    }
}

// ---- pass 2: LDS-staged y-slide + cc + reduce ----------------------------
__global__ __launch_bounds__(TPB_Y) void pass_y2(const unsigned char* __restrict__ A,
                                                 double* __restrict__ partials) {
    __shared__ unsigned char rows[YR * FROW];   // 38,400 B fp8
    __shared__ double sm[TPB_Y / 64];

    int blk = blockIdx.x;
    int yq = blk % NYQ;
    int z  = (blk / NYQ) % D;
    int b  = blk / (NYQ * D);
    int y0 = yq * YQ;
    int tid = threadIdx.x;
    const unsigned char* __restrict__ src =
        A + ((size_t)(b * D + z) * H) * FROW;

    // ---- stage 48 row-groups, coalesced uint4; OOB rows -> zero ----------
    for (int i = tid; i < LDW; i += TPB_Y) {
        int off = i * 16;
        int r = off / FROW;
        int gy = y0 - 4 + r;
        uint4 v = make_uint4(0u, 0u, 0u, 0u);
        if (gy >= 0 && gy < H)
            v = *(const uint4*)(src + (size_t)gy * FROW + (off % FROW));
        *(uint4*)&rows[off] = v;
    }
    __syncthreads();

    // ---- compute: 20 xg x 20 y-strips (2 outputs each), slide over LDS ---
    double acc = 0.0;
    if (tid < 400) {
        int xg = tid % 20;
        int ys = tid / 20;               // 0..19
        int rbase = ys * 2;              // local row of first tap
        int x8 = xg * 8;

        float s[5][8];
#pragma unroll
        for (int f = 0; f < 5; ++f)
#pragma unroll
            for (int i = 0; i < 8; ++i) s[f][i] = 0.f;

        // init 9-tap window: local rows rbase .. rbase+8
#pragma unroll
        for (int t = 0; t < 9; ++t) {
            const unsigned char* rp = &rows[(rbase + t) * FROW + x8];
#pragma unroll
            for (int f = 0; f < 5; ++f) {
                uint2 v = *(const uint2*)(rp + f * W);
                float u[8]; up8(v, u);
#pragma unroll
                for (int i = 0; i < 8; ++i) s[f][i] += u[i];
            }
        }

#pragma unroll
        for (int o = 0; o < 2; ++o) {
            float rowcc = 0.f;
#pragma unroll
            for (int i = 0; i < 8; ++i) {
                float Is = s[0][i], Js = s[1][i];
                float I2s = s[2][i], J2s = s[3][i], IJs = s[4][i];
                float tI = RW * Is;
                float cross = __builtin_fmaf(-tI, Js, IJs);
                float Iv    = __builtin_fmaf(-tI, Is, I2s);
                float Jv    = __builtin_fmaf(-(RW * Js), Js, J2s);
                float den   = __builtin_fmaf(Iv, Jv, 1e-5f);
                rowcc = __builtin_fmaf(cross * cross, __builtin_amdgcn_rcpf(den), rowcc);
            }
            acc += (double)rowcc;
            if (o == 0) {
                const unsigned char* re = &rows[(rbase + 9) * FROW + x8];
                const unsigned char* rl = &rows[rbase * FROW + x8];
#pragma unroll
                for (int f = 0; f < 5; ++f) {
                    uint2 ve = *(const uint2*)(re + f * W);
                    uint2 vl = *(const uint2*)(rl + f * W);
                    float ue[8], ul[8];
                    up8(ve, ue); up8(vl, ul);
#pragma unroll
                    for (int i = 0; i < 8; ++i) s[f][i] += ue[i] - ul[i];
                }
            }
        }
    }

    // ---- deterministic block reduction (7 waves; idle lanes acc=0) -------
#pragma unroll
    for (int off = 32; off > 0; off >>= 1) acc += __shfl_down(acc, off);
    if ((tid & 63) == 0) sm[tid >> 6] = acc;
    __syncthreads();
    if (tid == 0) {
        double tt = 0.0;
#pragma unroll
        for (int i = 0; i < TPB_Y / 64; ++i) tt += sm[i];
        partials[blockIdx.x] = tt;
    }
}

// ---- final deterministic reduce ------------------------------------------
__global__ __launch_bounds__(256) void finalize(const double* __restrict__ p,
                                                float* __restrict__ out) {
    double v = 0.0;
    for (int i = threadIdx.x; i < NBLK_Y; i += 256) v += p[i];
#pragma unroll
    for (int off = 32; off > 0; off >>= 1) v += __shfl_down(v, off);
    __shared__ double sm[4];
    int lane = threadIdx.x & 63, wid = threadIdx.x >> 6;
    if (lane == 0) sm[wid] = v;
    __syncthreads();
    if (threadIdx.x == 0) {
        double tt = 0.0;
#pragma unroll
        for (int i = 0; i < 4; ++i) tt += sm[i];
        out[0] = (float)(1.0 - tt / (double)((double)BATCH * (double)NVOX));
    }
}

extern "C" void kernel_launch(void* const* d_in, const int* in_sizes, int n_in,
                              void* d_out, int out_size, void* d_ws, size_t ws_size,
                              hipStream_t stream) {
    const float* I = (const float*)d_in[0];
    const float* J = (const float*)d_in[1];
    float* out = (float*)d_out;

    // ws: bufA (41 MB fp8, [b][z][y][f][x]) | partials (NBLK_Y f64)
    size_t bufsz = ((size_t)BATCH * 5 * NVOX + 255) / 256 * 256;
    unsigned char* bufA = (unsigned char*)d_ws;
    double* partials = (double*)(bufA + bufsz);

    pass_pzx<<<NBLK_P, TPB_P, 0, stream>>>(I, J, bufA);
    pass_y2<<<NBLK_Y, TPB_Y, 0, stream>>>(bufA, partials);
    finalize<<<1, 256, 0, stream>>>(partials, out);
}